// Round 15
// baseline (599.991 us; speedup 1.0000x reference)
//
#include <hip/hip_runtime.h>
#include <hip/hip_bf16.h>
#include <math.h>

#define NTOK 1024
#define DDIM 768
#define MDIM 3072
#define GN 4
#define EN 8
#define NEXP 32
#define NPAIR 8192
#define EPSW 1e-6f
#define MAXRB 96   // max 128-row blocks: 64 full + <=32 partials

typedef __attribute__((ext_vector_type(4))) float f32x4;
typedef __attribute__((ext_vector_type(4))) int   i32x4;
typedef __attribute__((ext_vector_type(4))) unsigned short u16x4;
typedef __attribute__((ext_vector_type(8))) __bf16 bf16x8;

__device__ __forceinline__ unsigned short f2bf(float f) {
  unsigned u = __builtin_bit_cast(unsigned, f);
  u += 0x7FFFu + ((u >> 16) & 1u);
  return (unsigned short)(u >> 16);
}

__device__ __forceinline__ void gld_lds16(const void* g, void* l) {
  __builtin_amdgcn_global_load_lds(
      (const __attribute__((address_space(1))) void*)g,
      (__attribute__((address_space(3))) void*)l, 16, 0, 0);
}

template<int N>
__device__ __forceinline__ void wait_vmcnt() {
  asm volatile("s_waitcnt vmcnt(%0)" :: "n"(N) : "memory");
}

// ---------------------------------------------------------------------------
// Init + zero-y + x->bf16.
// ---------------------------------------------------------------------------
__global__ void init_kernel(int* __restrict__ p) { p[threadIdx.x] = 0; }

__global__ __launch_bounds__(256) void zero_y(float* __restrict__ y) {
  ((f32x4*)y)[blockIdx.x * 256 + threadIdx.x] = (f32x4){0.f, 0.f, 0.f, 0.f};
}

__global__ __launch_bounds__(256) void x2bf(const float* __restrict__ x,
                                            unsigned short* __restrict__ xb) {
  const int i = (blockIdx.x * 256 + threadIdx.x) * 16;
#pragma unroll
  for (int j = 0; j < 4; ++j) {
    const f32x4 v = *(const f32x4*)(x + i + j * 4);
    u16x4 p = { f2bf(v.x), f2bf(v.y), f2bf(v.z), f2bf(v.w) };
    *(u16x4*)(xb + i + j * 4) = p;
  }
}

// ---------------------------------------------------------------------------
// Kernel 1: gating (proven correct).
// ---------------------------------------------------------------------------
__global__ __launch_bounds__(256) void gating_kernel(
    const float* __restrict__ x, const float* __restrict__ Wg,
    const float* __restrict__ bg, const float* __restrict__ We,
    const float* __restrict__ be, int* __restrict__ counts,
    int* __restrict__ pair_e, float* __restrict__ pair_w)
{
  __shared__ float xr[DDIM];
  __shared__ float logits[36];
  const int n = blockIdx.x;
  const int tid = threadIdx.x;
  const float* xp = x + (size_t)n * DDIM;
  for (int d = tid; d < DDIM; d += 256) xr[d] = xp[d];
  __syncthreads();

  const int w = tid >> 6, lane = tid & 63;
  for (int j = 0; j < 9; ++j) {
    const int o = w + 4 * j;  // 0..35
    float s = 0.f;
    if (o < 4) {
      for (int d = lane; d < DDIM; d += 64) s += xr[d] * Wg[d * GN + o];
    } else {
      const int g = (o - 4) >> 3, e = (o - 4) & 7;
      const float* wp = We + (size_t)g * DDIM * EN + e;
      for (int d = lane; d < DDIM; d += 64) s += xr[d] * wp[d * EN];
    }
    for (int off = 32; off; off >>= 1) s += __shfl_xor(s, off);
    if (lane == 0) logits[o] = s + ((o < 4) ? bg[o] : be[o - 4]);
  }
  __syncthreads();

  if (tid == 0) {
    float gl[4];
    for (int i = 0; i < 4; ++i) gl[i] = logits[i];
    int i0 = 0;
    for (int i = 1; i < 4; ++i) if (gl[i] > gl[i0]) i0 = i;
    int i1 = -1;
    for (int i = 0; i < 4; ++i) {
      if (i == i0) continue;
      if (i1 < 0 || gl[i] > gl[i1]) i1 = i;
    }
    const float m = gl[i0];
    const float e1 = expf(gl[i1] - m);
    const float s2 = 1.f + e1;
    float gv[2] = { 1.f / s2, e1 / s2 };
    int gi[2] = { i0, i1 };
    for (int r = 0; r < 2; ++r) if (gv[r] < EPSW) gv[r] = 0.f;

    for (int r = 0; r < 2; ++r) {
      const int g = gi[r];
      float el[8];
      for (int e = 0; e < 8; ++e) el[e] = logits[4 + g * 8 + e];
      int sel[4];
      for (int q = 0; q < 4; ++q) {
        int best = -1;
        for (int e = 0; e < 8; ++e) {
          bool used = false;
          for (int p = 0; p < q; ++p) if (sel[p] == e) used = true;
          if (used) continue;
          if (best < 0 || el[e] > el[best]) best = e;
        }
        sel[q] = best;
      }
      const float mm = el[sel[0]];
      float ex[4]; float ss = 0.f;
      for (int q = 0; q < 4; ++q) { ex[q] = expf(el[sel[q]] - mm); ss += ex[q]; }
      for (int q = 0; q < 4; ++q) {
        float ew = ex[q] / ss;
        if (ew < EPSW) ew = 0.f;
        const int gbl = g * 8 + sel[q];
        const int j = r * 4 + q;
        pair_e[n * 8 + j] = gbl;
        pair_w[n * 8 + j] = gv[r] * ew;
        atomicAdd(&counts[gbl], 1);
      }
    }
  }
}

// ---------------------------------------------------------------------------
// Kernel 2: scan + 128-row-block lookup table (rb -> expert, local by).
// ---------------------------------------------------------------------------
__global__ void scan_kernel(const int* __restrict__ counts, int* __restrict__ offsets,
                            int* __restrict__ rb_ge, int* __restrict__ rb_by,
                            int* __restrict__ nrb)
{
  if (threadIdx.x == 0) {
    int a = 0, n = 0;
    for (int e = 0; e < NEXP; ++e) {
      offsets[e] = a;
      const int c = counts[e];
      a += c;
      for (int b = 0; b * 128 < c; ++b) { rb_ge[n] = e; rb_by[n] = b; ++n; }
    }
    *nrb = n;
  }
}

// ---------------------------------------------------------------------------
// Kernel 3: slot bookkeeping (FC1 gathers token rows directly from xb).
// ---------------------------------------------------------------------------
__global__ __launch_bounds__(256) void scatter_kernel(
    const int* __restrict__ pair_e, const float* __restrict__ pair_w,
    const int* __restrict__ offsets, int* __restrict__ cursor,
    int* __restrict__ slot_tok, float* __restrict__ slot_w)
{
  const int idx = blockIdx.x * 256 + threadIdx.x;
  if (idx < NPAIR) {
    const int e = pair_e[idx];
    const int s = offsets[e] + atomicAdd(&cursor[e], 1);
    slot_tok[s] = idx >> 3;
    slot_w[s] = pair_w[idx];
  }
}

// ---------------------------------------------------------------------------
// Kernel 4: repack weights. in: [32][R][C] fp32 -> out: [32][C][R] bf16.
// Tiled 32x32 LDS transpose, measured 0 bank conflicts (round 3/5).
// ---------------------------------------------------------------------------
template<int R, int C>
__global__ __launch_bounds__(256) void repack_kernel(
    const float* __restrict__ W, unsigned short* __restrict__ Wt)
{
  __shared__ float tile[32][33];
  const int ge = blockIdx.z;
  const int rt = blockIdx.y, ct = blockIdx.x;
  const int tid = threadIdx.x;
  {
    const int r = tid >> 3, c4 = tid & 7;
    const f32x4 v = *(const f32x4*)(W + (size_t)ge * R * C
                                      + (size_t)(rt * 32 + r) * C + ct * 32 + c4 * 4);
#pragma unroll
    for (int j = 0; j < 4; ++j) tile[r][c4 * 4 + j] = v[j];
  }
  __syncthreads();
  {
    const int n = tid >> 3, k4 = tid & 7;
    u16x4 p;
    p.x = f2bf(tile[k4 * 4 + 0][n]);
    p.y = f2bf(tile[k4 * 4 + 1][n]);
    p.z = f2bf(tile[k4 * 4 + 2][n]);
    p.w = f2bf(tile[k4 * 4 + 3][n]);
    *(u16x4*)(Wt + (size_t)ge * R * C + (size_t)(ct * 32 + n) * R + rt * 32 + k4 * 4) = p;
  }
}

// ---------------------------------------------------------------------------
// Kernel 5: pure-bf16 GEMM, both operands k-contiguous, 3-DEEP pipeline.
// C[rows x NLD] = A_seg[rows x K] * Bt[ge][NLD x K]^T.
// BM=128, BN=128, BK=32, 4 waves, mfma 16x16x32 bf16.
// Per thread per K-step: exactly 4 global_load_lds x16B (A 2, Bt 2) —
// ZERO staging registers -> nothing can spill -> counted vmcnt is EXACT.
// THREE 16KB buffers (48KB LDS -> 3 blocks/CU): steady-state vmcnt(8)
// keeps tiles t+1 AND t+2 in flight while computing t — two compute
// phases (~600-1200cy) of latency cover vs HBM ~900cy. Buffer rotation
// static (NT%3==0): step t computes buf[t%3], then re-issues tile t+3
// into that same buffer after the second barrier. Tail waits 8->4->0.
// Swizzle s(r)=(r^(r>>2))&3 on 16B chunks (round-3: 0 conflicts).
// GATHER=1: A rows = xb[slot_tok[slot]] (FC1).  GATHER=0: A rows = H (FC2).
// EPI 0: H = bf16(gelu(C + b1)).  EPI 1: atomicAdd y[tok] += slot_w*(C+b2).
// ---------------------------------------------------------------------------
template<int K, int NLD, int EPI, int GATHER, int KS>
__global__ __launch_bounds__(256) void moe_gemm_bt3(
    const unsigned short* __restrict__ A, const unsigned short* __restrict__ Bt,
    const float* __restrict__ bias, const int* __restrict__ counts,
    const int* __restrict__ offsets, const float* __restrict__ slot_w,
    const int* __restrict__ slot_tok, const int* __restrict__ rb_ge,
    const int* __restrict__ rb_by, const int* __restrict__ nrb,
    unsigned short* __restrict__ Hout, float* __restrict__ Yout)
{
  constexpr int KC = K / KS;        // K-chunk
  constexpr int NT = KC / 32;       // K-steps: FC1 24, FC2 48 (KS=2); %3==0
  constexpr int ABY = 8192;         // A tile 128 x 64B
  constexpr int BUFB = 16384;       // + B tile 128 x 64B
  static_assert(NT % 3 == 0, "NT must be divisible by 3");

  const int rb = blockIdx.x;
  if (rb >= *nrb) return;
  const int ge = rb_ge[rb];
  const int by = rb_by[rb];
  const int cnt = counts[ge];
  const int off = offsets[ge];
  const int nb = blockIdx.y;
  const int ks = (KS > 1) ? blockIdx.z : 0;
  const int kbase = ks * KC;
  const int tid = threadIdx.x;

  __shared__ __align__(16) unsigned char lds[3 * BUFB];

  // ---- staging sources (pre-swizzled 16B chunk within each 64B k-row)
  const unsigned short* asrc[2];
  const unsigned short* bsrc[2];
#pragma unroll
  for (int i = 0; i < 2; ++i) {
    const int q = tid + 256 * i;
    const int m = q >> 2, c = q & 3;
    const int sc = c ^ ((m ^ (m >> 2)) & 3);
    int gr = by * 128 + m; if (gr >= cnt) gr = cnt - 1;
    const int row = GATHER ? slot_tok[off + gr] : (off + gr);
    asrc[i] = A + (size_t)row * K + kbase + sc * 8;
    bsrc[i] = Bt + (size_t)ge * NLD * K + (size_t)(nb * 128 + m) * K + kbase + sc * 8;
  }

  // ---- fragment geometry
  const int w = tid >> 6, lane = tid & 63;
  const int wr = (w >> 1) * 64, wc = (w & 1) * 64;
  const int l15 = lane & 15, l4 = lane >> 4;
  int aoff[4], boff[4];
#pragma unroll
  for (int mf = 0; mf < 4; ++mf) {
    const int m = wr + mf * 16 + l15;
    aoff[mf] = m * 64 + ((l4 ^ ((m ^ (m >> 2)) & 3)) * 16);
  }
#pragma unroll
  for (int nf = 0; nf < 4; ++nf) {
    const int n = wc + nf * 16 + l15;
    boff[nf] = ABY + n * 64 + ((l4 ^ ((n ^ (n >> 2)) & 3)) * 16);
  }

  f32x4 acc[4][4];
#pragma unroll
  for (int mf = 0; mf < 4; ++mf)
#pragma unroll
    for (int nf = 0; nf < 4; ++nf)
      acc[mf][nf] = (f32x4){0.f, 0.f, 0.f, 0.f};

#define ISSUE(T, B) { _Pragma("unroll") \
    for (int i = 0; i < 2; ++i) { \
      gld_lds16(asrc[i] + (size_t)(T) * 32, lds + (B) * BUFB + (tid + 256 * i) * 16); \
      gld_lds16(bsrc[i] + (size_t)(T) * 32, lds + (B) * BUFB + ABY + (tid + 256 * i) * 16); } }
#define COMPUTE(BASE) { bf16x8 afr[4], bfr[4]; _Pragma("unroll") \
    for (int mf = 0; mf < 4; ++mf) \
      afr[mf] = __builtin_bit_cast(bf16x8, *(const i32x4*)((BASE) + aoff[mf])); \
    _Pragma("unroll") \
    for (int nf = 0; nf < 4; ++nf) \
      bfr[nf] = __builtin_bit_cast(bf16x8, *(const i32x4*)((BASE) + boff[nf])); \
    _Pragma("unroll") \
    for (int mf = 0; mf < 4; ++mf) { _Pragma("unroll") \
      for (int nf = 0; nf < 4; ++nf) \
        acc[mf][nf] = __builtin_amdgcn_mfma_f32_16x16x32_bf16( \
            afr[mf], bfr[nf], acc[mf][nf], 0, 0, 0); } }
// One K-step. Steady state: after ISSUE(T+3) there are 12 loads in
// flight (tiles T+1,T+2,T+3). Before COMPUTE(T+1): vmcnt(8) retires
// tile T+1's 4 loads, leaves 8. Tail: T==NT-2 -> 4, T==NT-1 -> 0.
#define STEP3(T, B) { \
    if ((T) < NT - 2) { wait_vmcnt<8>(); } \
    else if ((T) == NT - 2) { wait_vmcnt<4>(); } \
    else { wait_vmcnt<0>(); } \
    __builtin_amdgcn_s_barrier(); \
    asm volatile("" ::: "memory"); \
    COMPUTE(lds + (B) * BUFB); \
    asm volatile("" ::: "memory"); \
    __builtin_amdgcn_s_barrier(); \
    if ((T) + 3 < NT) ISSUE((T) + 3, B); }

  // ---- prologue: tiles 0,1,2 into buffers 0,1,2 (12 loads in flight)
  ISSUE(0, 0);
  ISSUE(1, 1);
  ISSUE(2, 2);

  for (int t = 0; t < NT; t += 3) {
    STEP3(t + 0, 0);
    STEP3(t + 1, 1);
    STEP3(t + 2, 2);
  }
#undef ISSUE
#undef COMPUTE
#undef STEP3

  // ---- epilogue. C/D layout: col = lane&15, row = (lane>>4)*4 + j
#pragma unroll
  for (int mf = 0; mf < 4; ++mf) {
    const int rb2 = by * 128 + wr + mf * 16 + l4 * 4;
    if constexpr (EPI == 0) {
#pragma unroll
      for (int nf = 0; nf < 4; ++nf) {
        const int col = nb * 128 + wc + nf * 16 + l15;
        const float bv = bias[(size_t)ge * NLD + col];
#pragma unroll
        for (int j = 0; j < 4; ++j) {
          const int r = rb2 + j;
          if (r < cnt) {
            const float v = acc[mf][nf][j] + bv;
            const float gl = 0.5f * v * (1.f + erff(v * 0.70710678118654752f));
            Hout[(size_t)(off + r) * NLD + col] = f2bf(gl);
          }
        }
      }
    } else {
#pragma unroll
      for (int j = 0; j < 4; ++j) {
        const int r = rb2 + j;
        if (r < cnt) {
          const int slot = off + r;
          const float sw = slot_w[slot];
          const int tok = slot_tok[slot];
#pragma unroll
          for (int nf = 0; nf < 4; ++nf) {
            const int col = nb * 128 + wc + nf * 16 + l15;
            const float bv = (ks == 0) ? bias[(size_t)ge * NLD + col] : 0.f;
            atomicAdd(&Yout[(size_t)tok * DDIM + col], sw * (acc[mf][nf][j] + bv));
          }
        }
      }
    }
  }
}

// ---------------------------------------------------------------------------
// Workspace layout (bytes):
//   0    counts[32]     128  offsets[32]    256  cursor[32]   384 nrb
//   512  rb_ge[96]      896  rb_by[96]
//   2048 pair_e[8192]   34816 pair_w[8192]
//   67584 slot_tok[8192] 100352 slot_w[8192]
//   135168 xb[1024][768] bf16 (1.57 MB)
//   12715008 H[8192][3072] bf16 (50.3 MB)
//   63046656 Wt bf16 151MB (W1t for FC1, then W2t for FC2)
//   total ~214 MB (ws ~1.2 GB available)
// ---------------------------------------------------------------------------
extern "C" void kernel_launch(void* const* d_in, const int* in_sizes, int n_in,
                              void* d_out, int out_size, void* d_ws, size_t ws_size,
                              hipStream_t stream)
{
  const float* x  = (const float*)d_in[0];
  const float* Wg = (const float*)d_in[1];
  const float* bg = (const float*)d_in[2];
  const float* We = (const float*)d_in[3];
  const float* be = (const float*)d_in[4];
  const float* W1 = (const float*)d_in[5];
  const float* b1 = (const float*)d_in[6];
  const float* W2 = (const float*)d_in[7];
  const float* b2 = (const float*)d_in[8];
  float* y = (float*)d_out;

  char* ws = (char*)d_ws;
  int*   counts   = (int*)(ws + 0);
  int*   offsets  = (int*)(ws + 128);
  int*   cursor   = (int*)(ws + 256);
  int*   nrb      = (int*)(ws + 384);
  int*   rb_ge    = (int*)(ws + 512);
  int*   rb_by    = (int*)(ws + 896);
  int*   pair_e   = (int*)(ws + 2048);
  float* pair_w   = (float*)(ws + 34816);
  int*   slot_tok = (int*)(ws + 67584);
  float* slot_w   = (float*)(ws + 100352);
  unsigned short* xb = (unsigned short*)(ws + 135168);
  unsigned short* H  = (unsigned short*)(ws + 12715008);
  unsigned short* Wt = (unsigned short*)(ws + 63046656);

  init_kernel<<<1, 256, 0, stream>>>((int*)ws);
  zero_y<<<NTOK * DDIM / 1024, 256, 0, stream>>>(y);
  x2bf<<<NTOK * DDIM / 4096, 256, 0, stream>>>(x, xb);
  gating_kernel<<<NTOK, 256, 0, stream>>>(x, Wg, bg, We, be, counts, pair_e, pair_w);
  scan_kernel<<<1, 64, 0, stream>>>(counts, offsets, rb_ge, rb_by, nrb);
  scatter_kernel<<<NPAIR / 256, 256, 0, stream>>>(pair_e, pair_w, offsets, cursor,
                                                  slot_tok, slot_w);

  // FC1: repack W1 [768][3072] -> [3072][768] bf16, then pure-bf16 GEMM.
  repack_kernel<DDIM, MDIM><<<dim3(MDIM / 32, DDIM / 32, NEXP), 256, 0, stream>>>(W1, Wt);
  moe_gemm_bt3<DDIM, MDIM, 0, 1, 1><<<dim3(MAXRB, MDIM / 128, 1), 256, 0, stream>>>(
      xb, Wt, b1, counts, offsets, nullptr, slot_tok, rb_ge, rb_by, nrb, H, nullptr);
  // FC2: repack W2 [3072][768] -> [768][3072] bf16 (reuse Wt), then GEMM.
  repack_kernel<MDIM, DDIM><<<dim3(DDIM / 32, MDIM / 32, NEXP), 256, 0, stream>>>(W2, Wt);
  moe_gemm_bt3<MDIM, DDIM, 1, 0, 2><<<dim3(MAXRB, DDIM / 128, 2), 256, 0, stream>>>(
      H, Wt, b2, counts, offsets, slot_w, slot_tok, rb_ge, rb_by, nrb, nullptr, y);
}

// Round 16
// 551.878 us; speedup vs baseline: 1.0872x; 1.0872x over previous
//
#include <hip/hip_runtime.h>
#include <hip/hip_bf16.h>
#include <math.h>

#define NTOK 1024
#define DDIM 768
#define MDIM 3072
#define GN 4
#define EN 8
#define NEXP 32
#define NPAIR 8192
#define EPSW 1e-6f
#define MAXRB 96   // max 128-row blocks: 64 full + <=32 partials

typedef __attribute__((ext_vector_type(4))) float f32x4;
typedef __attribute__((ext_vector_type(4))) int   i32x4;
typedef __attribute__((ext_vector_type(4))) unsigned short u16x4;
typedef __attribute__((ext_vector_type(8))) __bf16 bf16x8;

__device__ __forceinline__ unsigned short f2bf(float f) {
  unsigned u = __builtin_bit_cast(unsigned, f);
  u += 0x7FFFu + ((u >> 16) & 1u);
  return (unsigned short)(u >> 16);
}

__device__ __forceinline__ void gld_lds16(const void* g, void* l) {
  __builtin_amdgcn_global_load_lds(
      (const __attribute__((address_space(1))) void*)g,
      (__attribute__((address_space(3))) void*)l, 16, 0, 0);
}

template<int N>
__device__ __forceinline__ void wait_vmcnt() {
  asm volatile("s_waitcnt vmcnt(%0)" :: "n"(N) : "memory");
}

// ---------------------------------------------------------------------------
// Kernel 0: fused prep — x->bf16 (blocks 0..191), zero y (192..959),
// zero control region (960). One launch instead of three.
// ---------------------------------------------------------------------------
__global__ __launch_bounds__(256) void prep_kernel(
    const float* __restrict__ x, unsigned short* __restrict__ xb,
    float* __restrict__ y, int* __restrict__ ctrl)
{
  const int b = blockIdx.x, tid = threadIdx.x;
  if (b < 192) {
    const int i = (b * 256 + tid) * 16;
#pragma unroll
    for (int j = 0; j < 4; ++j) {
      const f32x4 v = *(const f32x4*)(x + i + j * 4);
      u16x4 p = { f2bf(v.x), f2bf(v.y), f2bf(v.z), f2bf(v.w) };
      *(u16x4*)(xb + i + j * 4) = p;
    }
  } else if (b < 960) {
    ((f32x4*)y)[(b - 192) * 256 + tid] = (f32x4){0.f, 0.f, 0.f, 0.f};
  } else {
    ctrl[tid] = 0;
  }
}

// ---------------------------------------------------------------------------
// Kernel 1: gating (proven correct).
// ---------------------------------------------------------------------------
__global__ __launch_bounds__(256) void gating_kernel(
    const float* __restrict__ x, const float* __restrict__ Wg,
    const float* __restrict__ bg, const float* __restrict__ We,
    const float* __restrict__ be, int* __restrict__ counts,
    int* __restrict__ pair_e, float* __restrict__ pair_w)
{
  __shared__ float xr[DDIM];
  __shared__ float logits[36];
  const int n = blockIdx.x;
  const int tid = threadIdx.x;
  const float* xp = x + (size_t)n * DDIM;
  for (int d = tid; d < DDIM; d += 256) xr[d] = xp[d];
  __syncthreads();

  const int w = tid >> 6, lane = tid & 63;
  for (int j = 0; j < 9; ++j) {
    const int o = w + 4 * j;  // 0..35
    float s = 0.f;
    if (o < 4) {
      for (int d = lane; d < DDIM; d += 64) s += xr[d] * Wg[d * GN + o];
    } else {
      const int g = (o - 4) >> 3, e = (o - 4) & 7;
      const float* wp = We + (size_t)g * DDIM * EN + e;
      for (int d = lane; d < DDIM; d += 64) s += xr[d] * wp[d * EN];
    }
    for (int off = 32; off; off >>= 1) s += __shfl_xor(s, off);
    if (lane == 0) logits[o] = s + ((o < 4) ? bg[o] : be[o - 4]);
  }
  __syncthreads();

  if (tid == 0) {
    float gl[4];
    for (int i = 0; i < 4; ++i) gl[i] = logits[i];
    int i0 = 0;
    for (int i = 1; i < 4; ++i) if (gl[i] > gl[i0]) i0 = i;
    int i1 = -1;
    for (int i = 0; i < 4; ++i) {
      if (i == i0) continue;
      if (i1 < 0 || gl[i] > gl[i1]) i1 = i;
    }
    const float m = gl[i0];
    const float e1 = expf(gl[i1] - m);
    const float s2 = 1.f + e1;
    float gv[2] = { 1.f / s2, e1 / s2 };
    int gi[2] = { i0, i1 };
    for (int r = 0; r < 2; ++r) if (gv[r] < EPSW) gv[r] = 0.f;

    for (int r = 0; r < 2; ++r) {
      const int g = gi[r];
      float el[8];
      for (int e = 0; e < 8; ++e) el[e] = logits[4 + g * 8 + e];
      int sel[4];
      for (int q = 0; q < 4; ++q) {
        int best = -1;
        for (int e = 0; e < 8; ++e) {
          bool used = false;
          for (int p = 0; p < q; ++p) if (sel[p] == e) used = true;
          if (used) continue;
          if (best < 0 || el[e] > el[best]) best = e;
        }
        sel[q] = best;
      }
      const float mm = el[sel[0]];
      float ex[4]; float ss = 0.f;
      for (int q = 0; q < 4; ++q) { ex[q] = expf(el[sel[q]] - mm); ss += ex[q]; }
      for (int q = 0; q < 4; ++q) {
        float ew = ex[q] / ss;
        if (ew < EPSW) ew = 0.f;
        const int gbl = g * 8 + sel[q];
        const int j = r * 4 + q;
        pair_e[n * 8 + j] = gbl;
        pair_w[n * 8 + j] = gv[r] * ew;
        atomicAdd(&counts[gbl], 1);
      }
    }
  }
}

// ---------------------------------------------------------------------------
// Kernel 2: scan + 128-row-block lookup table (rb -> expert, local by).
// ---------------------------------------------------------------------------
__global__ void scan_kernel(const int* __restrict__ counts, int* __restrict__ offsets,
                            int* __restrict__ rb_ge, int* __restrict__ rb_by,
                            int* __restrict__ nrb)
{
  if (threadIdx.x == 0) {
    int a = 0, n = 0;
    for (int e = 0; e < NEXP; ++e) {
      offsets[e] = a;
      const int c = counts[e];
      a += c;
      for (int b = 0; b * 128 < c; ++b) { rb_ge[n] = e; rb_by[n] = b; ++n; }
    }
    *nrb = n;
  }
}

// ---------------------------------------------------------------------------
// Kernel 3: slot bookkeeping (FC1 gathers token rows directly from xb).
// ---------------------------------------------------------------------------
__global__ __launch_bounds__(256) void scatter_kernel(
    const int* __restrict__ pair_e, const float* __restrict__ pair_w,
    const int* __restrict__ offsets, int* __restrict__ cursor,
    int* __restrict__ slot_tok, float* __restrict__ slot_w)
{
  const int idx = blockIdx.x * 256 + threadIdx.x;
  if (idx < NPAIR) {
    const int e = pair_e[idx];
    const int s = offsets[e] + atomicAdd(&cursor[e], 1);
    slot_tok[s] = idx >> 3;
    slot_w[s] = pair_w[idx];
  }
}

// ---------------------------------------------------------------------------
// Kernel 4: repack weights. in: [32][R][C] fp32 -> out: [32][C][R] bf16.
// Tiled 32x32 LDS transpose, measured 0 bank conflicts (round 3/5).
// ---------------------------------------------------------------------------
template<int R, int C>
__global__ __launch_bounds__(256) void repack_kernel(
    const float* __restrict__ W, unsigned short* __restrict__ Wt)
{
  __shared__ float tile[32][33];
  const int ge = blockIdx.z;
  const int rt = blockIdx.y, ct = blockIdx.x;
  const int tid = threadIdx.x;
  {
    const int r = tid >> 3, c4 = tid & 7;
    const f32x4 v = *(const f32x4*)(W + (size_t)ge * R * C
                                      + (size_t)(rt * 32 + r) * C + ct * 32 + c4 * 4);
#pragma unroll
    for (int j = 0; j < 4; ++j) tile[r][c4 * 4 + j] = v[j];
  }
  __syncthreads();
  {
    const int n = tid >> 3, k4 = tid & 7;
    u16x4 p;
    p.x = f2bf(tile[k4 * 4 + 0][n]);
    p.y = f2bf(tile[k4 * 4 + 1][n]);
    p.z = f2bf(tile[k4 * 4 + 2][n]);
    p.w = f2bf(tile[k4 * 4 + 3][n]);
    *(u16x4*)(Wt + (size_t)ge * R * C + (size_t)(ct * 32 + n) * R + rt * 32 + k4 * 4) = p;
  }
}

// ---------------------------------------------------------------------------
// Kernel 5: pure-bf16 GEMM, both operands k-contiguous, double-buffered.
// C[rows x NLD] = A_seg[rows x K] * Bt[ge][NLD x K]^T.
// BM=128, BN=128, BK=32, 4 waves, mfma 16x16x32 bf16.
// Per thread per K-step: exactly 4 global_load_lds x16B (A 2, Bt 2) —
// ZERO staging registers -> nothing can spill -> counted vmcnt(4) EXACT.
// True VGPR need ~110 (acc 64 + frags 32 + addr), so __launch_bounds__
// (256,4) [128 VGPR cap] fits WITHOUT spilling (unlike the register-
// staged r10 kernel) -> 4 blocks/CU (16 waves), LDS 32KB*4=128KB OK.
// This attacks the 15%-occupancy invariant seen in rounds 8-15.
// Swizzle s(r)=(r^(r>>2))&3 on 16B chunks (round-3: 0 conflicts).
// GATHER=1: A rows = xb[slot_tok[slot]] (FC1).  GATHER=0: A rows = H (FC2).
// EPI 0: H = bf16(gelu(C + b1)).  EPI 1: atomicAdd y[tok] += slot_w*(C+b2).
// ---------------------------------------------------------------------------
template<int K, int NLD, int EPI, int GATHER, int KS>
__global__ __launch_bounds__(256, 4) void moe_gemm_bt2(
    const unsigned short* __restrict__ A, const unsigned short* __restrict__ Bt,
    const float* __restrict__ bias, const int* __restrict__ counts,
    const int* __restrict__ offsets, const float* __restrict__ slot_w,
    const int* __restrict__ slot_tok, const int* __restrict__ rb_ge,
    const int* __restrict__ rb_by, const int* __restrict__ nrb,
    unsigned short* __restrict__ Hout, float* __restrict__ Yout)
{
  constexpr int KC = K / KS;        // K-chunk
  constexpr int NT = KC / 32;       // K-steps: FC1 24, FC2 48 (KS=2)
  constexpr int ABY = 8192;         // A tile 128 x 64B
  constexpr int BUFB = 16384;       // + B tile 128 x 64B

  const int rb = blockIdx.x;
  if (rb >= *nrb) return;
  const int ge = rb_ge[rb];
  const int by = rb_by[rb];
  const int cnt = counts[ge];
  const int off = offsets[ge];
  const int nb = blockIdx.y;
  const int ks = (KS > 1) ? blockIdx.z : 0;
  const int kbase = ks * KC;
  const int tid = threadIdx.x;

  __shared__ __align__(16) unsigned char lds[2 * BUFB];

  // ---- staging sources (pre-swizzled 16B chunk within each 64B k-row)
  const unsigned short* asrc[2];
  const unsigned short* bsrc[2];
#pragma unroll
  for (int i = 0; i < 2; ++i) {
    const int q = tid + 256 * i;
    const int m = q >> 2, c = q & 3;
    const int sc = c ^ ((m ^ (m >> 2)) & 3);
    int gr = by * 128 + m; if (gr >= cnt) gr = cnt - 1;
    const int row = GATHER ? slot_tok[off + gr] : (off + gr);
    asrc[i] = A + (size_t)row * K + kbase + sc * 8;
    bsrc[i] = Bt + (size_t)ge * NLD * K + (size_t)(nb * 128 + m) * K + kbase + sc * 8;
  }

  // ---- fragment geometry
  const int w = tid >> 6, lane = tid & 63;
  const int wr = (w >> 1) * 64, wc = (w & 1) * 64;
  const int l15 = lane & 15, l4 = lane >> 4;
  int aoff[4], boff[4];
#pragma unroll
  for (int mf = 0; mf < 4; ++mf) {
    const int m = wr + mf * 16 + l15;
    aoff[mf] = m * 64 + ((l4 ^ ((m ^ (m >> 2)) & 3)) * 16);
  }
#pragma unroll
  for (int nf = 0; nf < 4; ++nf) {
    const int n = wc + nf * 16 + l15;
    boff[nf] = ABY + n * 64 + ((l4 ^ ((n ^ (n >> 2)) & 3)) * 16);
  }

  f32x4 acc[4][4];
#pragma unroll
  for (int mf = 0; mf < 4; ++mf)
#pragma unroll
    for (int nf = 0; nf < 4; ++nf)
      acc[mf][nf] = (f32x4){0.f, 0.f, 0.f, 0.f};

#define ISSUE(T, B) { _Pragma("unroll") \
    for (int i = 0; i < 2; ++i) { \
      gld_lds16(asrc[i] + (size_t)(T) * 32, lds + (B) * BUFB + (tid + 256 * i) * 16); \
      gld_lds16(bsrc[i] + (size_t)(T) * 32, lds + (B) * BUFB + ABY + (tid + 256 * i) * 16); } }
#define COMPUTE(BASE) { bf16x8 afr[4], bfr[4]; _Pragma("unroll") \
    for (int mf = 0; mf < 4; ++mf) \
      afr[mf] = __builtin_bit_cast(bf16x8, *(const i32x4*)((BASE) + aoff[mf])); \
    _Pragma("unroll") \
    for (int nf = 0; nf < 4; ++nf) \
      bfr[nf] = __builtin_bit_cast(bf16x8, *(const i32x4*)((BASE) + boff[nf])); \
    _Pragma("unroll") \
    for (int mf = 0; mf < 4; ++mf) { _Pragma("unroll") \
      for (int nf = 0; nf < 4; ++nf) \
        acc[mf][nf] = __builtin_amdgcn_mfma_f32_16x16x32_bf16( \
            afr[mf], bfr[nf], acc[mf][nf], 0, 0, 0); } }

  // ---- prologue: tiles 0,1
  ISSUE(0, 0);
  ISSUE(1, 1);

  for (int t = 0; t < NT; ++t) {
    if (t + 1 < NT) wait_vmcnt<4>(); else wait_vmcnt<0>();
    __builtin_amdgcn_s_barrier();
    asm volatile("" ::: "memory");
    COMPUTE(lds + (t & 1) * BUFB);
    asm volatile("" ::: "memory");
    __builtin_amdgcn_s_barrier();
    if (t + 2 < NT) ISSUE(t + 2, t & 1);
  }
#undef ISSUE
#undef COMPUTE

  // ---- epilogue. C/D layout: col = lane&15, row = (lane>>4)*4 + j
#pragma unroll
  for (int mf = 0; mf < 4; ++mf) {
    const int rb2 = by * 128 + wr + mf * 16 + l4 * 4;
    if constexpr (EPI == 0) {
#pragma unroll
      for (int nf = 0; nf < 4; ++nf) {
        const int col = nb * 128 + wc + nf * 16 + l15;
        const float bv = bias[(size_t)ge * NLD + col];
#pragma unroll
        for (int j = 0; j < 4; ++j) {
          const int r = rb2 + j;
          if (r < cnt) {
            const float v = acc[mf][nf][j] + bv;
            const float gl = 0.5f * v * (1.f + erff(v * 0.70710678118654752f));
            Hout[(size_t)(off + r) * NLD + col] = f2bf(gl);
          }
        }
      }
    } else {
#pragma unroll
      for (int j = 0; j < 4; ++j) {
        const int r = rb2 + j;
        if (r < cnt) {
          const int slot = off + r;
          const float sw = slot_w[slot];
          const int tok = slot_tok[slot];
#pragma unroll
          for (int nf = 0; nf < 4; ++nf) {
            const int col = nb * 128 + wc + nf * 16 + l15;
            const float bv = (ks == 0) ? bias[(size_t)ge * NLD + col] : 0.f;
            atomicAdd(&Yout[(size_t)tok * DDIM + col], sw * (acc[mf][nf][j] + bv));
          }
        }
      }
    }
  }
}

// ---------------------------------------------------------------------------
// Workspace layout (bytes):
//   0    counts[32]     128  offsets[32]    256  cursor[32]   384 nrb
//   512  rb_ge[96]      896  rb_by[96]
//   2048 pair_e[8192]   34816 pair_w[8192]
//   67584 slot_tok[8192] 100352 slot_w[8192]
//   135168 xb[1024][768] bf16 (1.57 MB)
//   12715008 H[8192][3072] bf16 (50.3 MB)
//   63046656 Wt bf16 151MB (W1t for FC1, then W2t for FC2)
//   total ~214 MB (ws ~1.2 GB available)
// ---------------------------------------------------------------------------
extern "C" void kernel_launch(void* const* d_in, const int* in_sizes, int n_in,
                              void* d_out, int out_size, void* d_ws, size_t ws_size,
                              hipStream_t stream)
{
  const float* x  = (const float*)d_in[0];
  const float* Wg = (const float*)d_in[1];
  const float* bg = (const float*)d_in[2];
  const float* We = (const float*)d_in[3];
  const float* be = (const float*)d_in[4];
  const float* W1 = (const float*)d_in[5];
  const float* b1 = (const float*)d_in[6];
  const float* W2 = (const float*)d_in[7];
  const float* b2 = (const float*)d_in[8];
  float* y = (float*)d_out;

  char* ws = (char*)d_ws;
  int*   counts   = (int*)(ws + 0);
  int*   offsets  = (int*)(ws + 128);
  int*   cursor   = (int*)(ws + 256);
  int*   nrb      = (int*)(ws + 384);
  int*   rb_ge    = (int*)(ws + 512);
  int*   rb_by    = (int*)(ws + 896);
  int*   pair_e   = (int*)(ws + 2048);
  float* pair_w   = (float*)(ws + 34816);
  int*   slot_tok = (int*)(ws + 67584);
  float* slot_w   = (float*)(ws + 100352);
  unsigned short* xb = (unsigned short*)(ws + 135168);
  unsigned short* H  = (unsigned short*)(ws + 12715008);
  unsigned short* Wt = (unsigned short*)(ws + 63046656);

  prep_kernel<<<961, 256, 0, stream>>>(x, xb, y, (int*)ws);
  gating_kernel<<<NTOK, 256, 0, stream>>>(x, Wg, bg, We, be, counts, pair_e, pair_w);
  scan_kernel<<<1, 64, 0, stream>>>(counts, offsets, rb_ge, rb_by, nrb);
  scatter_kernel<<<NPAIR / 256, 256, 0, stream>>>(pair_e, pair_w, offsets, cursor,
                                                  slot_tok, slot_w);

  // FC1: repack W1 [768][3072] -> [3072][768] bf16, then pure-bf16 GEMM.
  repack_kernel<DDIM, MDIM><<<dim3(MDIM / 32, DDIM / 32, NEXP), 256, 0, stream>>>(W1, Wt);
  moe_gemm_bt2<DDIM, MDIM, 0, 1, 1><<<dim3(MAXRB, MDIM / 128, 1), 256, 0, stream>>>(
      xb, Wt, b1, counts, offsets, nullptr, slot_tok, rb_ge, rb_by, nrb, H, nullptr);
  // FC2: repack W2 [3072][768] -> [768][3072] bf16 (reuse Wt), then GEMM.
  repack_kernel<MDIM, DDIM><<<dim3(DDIM / 32, MDIM / 32, NEXP), 256, 0, stream>>>(W2, Wt);
  moe_gemm_bt2<MDIM, DDIM, 1, 0, 2><<<dim3(MAXRB, DDIM / 128, 2), 256, 0, stream>>>(
      H, Wt, b2, counts, offsets, slot_w, slot_tok, rb_ge, rb_by, nrb, nullptr, y);
}

// Round 17
// 534.295 us; speedup vs baseline: 1.1230x; 1.0329x over previous
//
#include <hip/hip_runtime.h>
#include <hip/hip_bf16.h>
#include <math.h>

#define NTOK 1024
#define DDIM 768
#define MDIM 3072
#define GN 4
#define EN 8
#define NEXP 32
#define NPAIR 8192
#define EPSW 1e-6f
#define MAXRB 96   // max 128-row blocks: 64 full + <=32 partials

typedef __attribute__((ext_vector_type(4))) float f32x4;
typedef __attribute__((ext_vector_type(4))) int   i32x4;
typedef __attribute__((ext_vector_type(4))) unsigned short u16x4;
typedef __attribute__((ext_vector_type(8))) __bf16 bf16x8;

__device__ __forceinline__ unsigned short f2bf(float f) {
  unsigned u = __builtin_bit_cast(unsigned, f);
  u += 0x7FFFu + ((u >> 16) & 1u);
  return (unsigned short)(u >> 16);
}

__device__ __forceinline__ void gld_lds16(const void* g, void* l) {
  __builtin_amdgcn_global_load_lds(
      (const __attribute__((address_space(1))) void*)g,
      (__attribute__((address_space(3))) void*)l, 16, 0, 0);
}

template<int N>
__device__ __forceinline__ void wait_vmcnt() {
  asm volatile("s_waitcnt vmcnt(%0)" :: "n"(N) : "memory");
}

// ---------------------------------------------------------------------------
// Repack body (proven 0-conflict 32x32 LDS transpose): W [ge][R][C] fp32
// -> Wt [ge][C][R] bf16. tile = 32x33 floats in shared.
// ---------------------------------------------------------------------------
template<int R, int C>
__device__ __forceinline__ void repack_body(
    float* tile, const float* __restrict__ W, unsigned short* __restrict__ Wt,
    int ge, int rt, int ct)
{
  const int tid = threadIdx.x;
  {
    const int r = tid >> 3, c4 = tid & 7;
    const f32x4 v = *(const f32x4*)(W + (size_t)ge * R * C
                                      + (size_t)(rt * 32 + r) * C + ct * 32 + c4 * 4);
#pragma unroll
    for (int j = 0; j < 4; ++j) tile[r * 33 + c4 * 4 + j] = v[j];
  }
  __syncthreads();
  {
    const int n = tid >> 3, k4 = tid & 7;
    u16x4 p;
    p.x = f2bf(tile[(k4 * 4 + 0) * 33 + n]);
    p.y = f2bf(tile[(k4 * 4 + 1) * 33 + n]);
    p.z = f2bf(tile[(k4 * 4 + 2) * 33 + n]);
    p.w = f2bf(tile[(k4 * 4 + 3) * 33 + n]);
    *(u16x4*)(Wt + (size_t)ge * R * C + (size_t)(ct * 32 + n) * R + rt * 32 + k4 * 4) = p;
  }
}

// ---------------------------------------------------------------------------
// Phase 1 megakernel: all mutually-independent pre-GEMM work in ONE launch
// so the two weight repacks (906 MB streaming) hide gating/prep under them
// instead of sitting serially in the chain.
//   blocks [0,192)            x -> bf16
//   blocks [192,960)          zero y
//   block  960                zero ctrl
//   blocks [961,1985)         gating (one block per token)
//   blocks [1985,+73728)      repack W1 [768][3072] -> W1t [3072][768]
//   blocks [75713,+73728)     repack W2 [3072][768] -> W2t [768][3072]
// ---------------------------------------------------------------------------
__global__ __launch_bounds__(256) void phase1_kernel(
    const float* __restrict__ x, unsigned short* __restrict__ xb,
    float* __restrict__ y, int* __restrict__ ctrl,
    const float* __restrict__ Wg, const float* __restrict__ bg,
    const float* __restrict__ We, const float* __restrict__ be,
    int* __restrict__ counts, int* __restrict__ pair_e, float* __restrict__ pair_w,
    const float* __restrict__ W1, unsigned short* __restrict__ W1t,
    const float* __restrict__ W2, unsigned short* __restrict__ W2t)
{
  __shared__ __align__(16) float shm[1056];   // 4224 B: repack tile / gating xr+logits
  const int b = blockIdx.x;
  const int tid = threadIdx.x;

  if (b < 192) {                    // ---- x -> bf16
    const int i = (b * 256 + tid) * 16;
#pragma unroll
    for (int j = 0; j < 4; ++j) {
      const f32x4 v = *(const f32x4*)(x + i + j * 4);
      u16x4 p = { f2bf(v.x), f2bf(v.y), f2bf(v.z), f2bf(v.w) };
      *(u16x4*)(xb + i + j * 4) = p;
    }
    return;
  }
  if (b < 960) {                    // ---- zero y
    ((f32x4*)y)[(b - 192) * 256 + tid] = (f32x4){0.f, 0.f, 0.f, 0.f};
    return;
  }
  if (b == 960) {                   // ---- zero control region
    ctrl[tid] = 0;
    return;
  }
  if (b < 1985) {                   // ---- gating (proven correct)
    float* xr = shm;                // [768]
    float* logits = shm + 768;      // [36]
    const int n = b - 961;
    const float* xp = x + (size_t)n * DDIM;
    for (int d = tid; d < DDIM; d += 256) xr[d] = xp[d];
    __syncthreads();

    const int w = tid >> 6, lane = tid & 63;
    for (int j = 0; j < 9; ++j) {
      const int o = w + 4 * j;  // 0..35
      float s = 0.f;
      if (o < 4) {
        for (int d = lane; d < DDIM; d += 64) s += xr[d] * Wg[d * GN + o];
      } else {
        const int g = (o - 4) >> 3, e = (o - 4) & 7;
        const float* wp = We + (size_t)g * DDIM * EN + e;
        for (int d = lane; d < DDIM; d += 64) s += xr[d] * wp[d * EN];
      }
      for (int off = 32; off; off >>= 1) s += __shfl_xor(s, off);
      if (lane == 0) logits[o] = s + ((o < 4) ? bg[o] : be[o - 4]);
    }
    __syncthreads();

    if (tid == 0) {
      float gl[4];
      for (int i = 0; i < 4; ++i) gl[i] = logits[i];
      int i0 = 0;
      for (int i = 1; i < 4; ++i) if (gl[i] > gl[i0]) i0 = i;
      int i1 = -1;
      for (int i = 0; i < 4; ++i) {
        if (i == i0) continue;
        if (i1 < 0 || gl[i] > gl[i1]) i1 = i;
      }
      const float m = gl[i0];
      const float e1 = expf(gl[i1] - m);
      const float s2 = 1.f + e1;
      float gv[2] = { 1.f / s2, e1 / s2 };
      int gi[2] = { i0, i1 };
      for (int r = 0; r < 2; ++r) if (gv[r] < EPSW) gv[r] = 0.f;

      for (int r = 0; r < 2; ++r) {
        const int g = gi[r];
        float el[8];
        for (int e = 0; e < 8; ++e) el[e] = logits[4 + g * 8 + e];
        int sel[4];
        for (int q = 0; q < 4; ++q) {
          int best = -1;
          for (int e = 0; e < 8; ++e) {
            bool used = false;
            for (int p = 0; p < q; ++p) if (sel[p] == e) used = true;
            if (used) continue;
            if (best < 0 || el[e] > el[best]) best = e;
          }
          sel[q] = best;
        }
        const float mm = el[sel[0]];
        float ex[4]; float ss = 0.f;
        for (int q = 0; q < 4; ++q) { ex[q] = expf(el[sel[q]] - mm); ss += ex[q]; }
        for (int q = 0; q < 4; ++q) {
          float ew = ex[q] / ss;
          if (ew < EPSW) ew = 0.f;
          const int gbl = g * 8 + sel[q];
          const int j = r * 4 + q;
          pair_e[n * 8 + j] = gbl;
          pair_w[n * 8 + j] = gv[r] * ew;
          atomicAdd(&counts[gbl], 1);
        }
      }
    }
    return;
  }
  if (b < 75713) {                  // ---- repack W1: grid (96,24,32)
    const int i = b - 1985;
    repack_body<DDIM, MDIM>(shm, W1, W1t, i / 2304, (i / 96) % 24, i % 96);
    return;
  }
  {                                 // ---- repack W2: grid (24,96,32)
    const int i = b - 75713;
    repack_body<MDIM, DDIM>(shm, W2, W2t, i / 2304, (i / 24) % 96, i % 24);
  }
}

// ---------------------------------------------------------------------------
// Kernel 2: scan + 128-row-block lookup table (rb -> expert, local by).
// ---------------------------------------------------------------------------
__global__ void scan_kernel(const int* __restrict__ counts, int* __restrict__ offsets,
                            int* __restrict__ rb_ge, int* __restrict__ rb_by,
                            int* __restrict__ nrb)
{
  if (threadIdx.x == 0) {
    int a = 0, n = 0;
    for (int e = 0; e < NEXP; ++e) {
      offsets[e] = a;
      const int c = counts[e];
      a += c;
      for (int b = 0; b * 128 < c; ++b) { rb_ge[n] = e; rb_by[n] = b; ++n; }
    }
    *nrb = n;
  }
}

// ---------------------------------------------------------------------------
// Kernel 3: slot bookkeeping (FC1 gathers token rows directly from xb).
// ---------------------------------------------------------------------------
__global__ __launch_bounds__(256) void scatter_kernel(
    const int* __restrict__ pair_e, const float* __restrict__ pair_w,
    const int* __restrict__ offsets, int* __restrict__ cursor,
    int* __restrict__ slot_tok, float* __restrict__ slot_w)
{
  const int idx = blockIdx.x * 256 + threadIdx.x;
  if (idx < NPAIR) {
    const int e = pair_e[idx];
    const int s = offsets[e] + atomicAdd(&cursor[e], 1);
    slot_tok[s] = idx >> 3;
    slot_w[s] = pair_w[idx];
  }
}

// ---------------------------------------------------------------------------
// GEMM body (r16-proven, byte-identical inner loop): pure-bf16, both
// operands k-contiguous, double-buffered, 4 global_load_lds/thread/K-step,
// ZERO staging registers -> counted vmcnt(4) exact.
// ---------------------------------------------------------------------------
template<int K, int NLD, int EPI, int GATHER, int KS>
__device__ __forceinline__ void gemm_body(
    unsigned char* lds,
    const unsigned short* __restrict__ A, const unsigned short* __restrict__ Bt,
    const float* __restrict__ bias, const int* __restrict__ counts,
    const int* __restrict__ offsets, const float* __restrict__ slot_w,
    const int* __restrict__ slot_tok, const int* __restrict__ rb_ge,
    const int* __restrict__ rb_by, const int* __restrict__ nrb,
    unsigned short* __restrict__ Hout, float* __restrict__ Yout,
    int rb, int nb, int ks)
{
  constexpr int KC = K / KS;
  constexpr int NT = KC / 32;
  constexpr int ABY = 8192;
  constexpr int BUFB = 16384;

  if (rb >= *nrb) return;
  const int ge = rb_ge[rb];
  const int by = rb_by[rb];
  const int cnt = counts[ge];
  const int off = offsets[ge];
  const int kbase = ks * KC;
  const int tid = threadIdx.x;

  const unsigned short* asrc[2];
  const unsigned short* bsrc[2];
#pragma unroll
  for (int i = 0; i < 2; ++i) {
    const int q = tid + 256 * i;
    const int m = q >> 2, c = q & 3;
    const int sc = c ^ ((m ^ (m >> 2)) & 3);
    int gr = by * 128 + m; if (gr >= cnt) gr = cnt - 1;
    const int row = GATHER ? slot_tok[off + gr] : (off + gr);
    asrc[i] = A + (size_t)row * K + kbase + sc * 8;
    bsrc[i] = Bt + (size_t)ge * NLD * K + (size_t)(nb * 128 + m) * K + kbase + sc * 8;
  }

  const int w = tid >> 6, lane = tid & 63;
  const int wr = (w >> 1) * 64, wc = (w & 1) * 64;
  const int l15 = lane & 15, l4 = lane >> 4;
  int aoff[4], boff[4];
#pragma unroll
  for (int mf = 0; mf < 4; ++mf) {
    const int m = wr + mf * 16 + l15;
    aoff[mf] = m * 64 + ((l4 ^ ((m ^ (m >> 2)) & 3)) * 16);
  }
#pragma unroll
  for (int nf = 0; nf < 4; ++nf) {
    const int n = wc + nf * 16 + l15;
    boff[nf] = ABY + n * 64 + ((l4 ^ ((n ^ (n >> 2)) & 3)) * 16);
  }

  f32x4 acc[4][4];
#pragma unroll
  for (int mf = 0; mf < 4; ++mf)
#pragma unroll
    for (int nf = 0; nf < 4; ++nf)
      acc[mf][nf] = (f32x4){0.f, 0.f, 0.f, 0.f};

#define ISSUE(T, B) { _Pragma("unroll") \
    for (int i = 0; i < 2; ++i) { \
      gld_lds16(asrc[i] + (size_t)(T) * 32, lds + (B) * BUFB + (tid + 256 * i) * 16); \
      gld_lds16(bsrc[i] + (size_t)(T) * 32, lds + (B) * BUFB + ABY + (tid + 256 * i) * 16); } }
#define COMPUTE(BASE) { bf16x8 afr[4], bfr[4]; _Pragma("unroll") \
    for (int mf = 0; mf < 4; ++mf) \
      afr[mf] = __builtin_bit_cast(bf16x8, *(const i32x4*)((BASE) + aoff[mf])); \
    _Pragma("unroll") \
    for (int nf = 0; nf < 4; ++nf) \
      bfr[nf] = __builtin_bit_cast(bf16x8, *(const i32x4*)((BASE) + boff[nf])); \
    _Pragma("unroll") \
    for (int mf = 0; mf < 4; ++mf) { _Pragma("unroll") \
      for (int nf = 0; nf < 4; ++nf) \
        acc[mf][nf] = __builtin_amdgcn_mfma_f32_16x16x32_bf16( \
            afr[mf], bfr[nf], acc[mf][nf], 0, 0, 0); } }

  ISSUE(0, 0);
  ISSUE(1, 1);

  for (int t = 0; t < NT; ++t) {
    if (t + 1 < NT) wait_vmcnt<4>(); else wait_vmcnt<0>();
    __builtin_amdgcn_s_barrier();
    asm volatile("" ::: "memory");
    COMPUTE(lds + (t & 1) * BUFB);
    asm volatile("" ::: "memory");
    __builtin_amdgcn_s_barrier();
    if (t + 2 < NT) ISSUE(t + 2, t & 1);
  }
#undef ISSUE
#undef COMPUTE

  // epilogue. C/D layout: col = lane&15, row = (lane>>4)*4 + j
#pragma unroll
  for (int mf = 0; mf < 4; ++mf) {
    const int rb2 = by * 128 + wr + mf * 16 + l4 * 4;
    if constexpr (EPI == 0) {
#pragma unroll
      for (int nf = 0; nf < 4; ++nf) {
        const int col = nb * 128 + wc + nf * 16 + l15;
        const float bv = bias[(size_t)ge * NLD + col];
#pragma unroll
        for (int j = 0; j < 4; ++j) {
          const int r = rb2 + j;
          if (r < cnt) {
            const float v = acc[mf][nf][j] + bv;
            const float gl = 0.5f * v * (1.f + erff(v * 0.70710678118654752f));
            Hout[(size_t)(off + r) * NLD + col] = f2bf(gl);
          }
        }
      }
    } else {
#pragma unroll
      for (int j = 0; j < 4; ++j) {
        const int r = rb2 + j;
        if (r < cnt) {
          const int slot = off + r;
          const float sw = slot_w[slot];
          const int tok = slot_tok[slot];
#pragma unroll
          for (int nf = 0; nf < 4; ++nf) {
            const int col = nb * 128 + wc + nf * 16 + l15;
            const float bv = (ks == 0) ? bias[(size_t)ge * NLD + col] : 0.f;
            atomicAdd(&Yout[(size_t)tok * DDIM + col], sw * (acc[mf][nf][j] + bv));
          }
        }
      }
    }
  }
}

// ---------------------------------------------------------------------------
// FC1 / FC2 wrappers.
// ---------------------------------------------------------------------------
__global__ __launch_bounds__(256, 4) void fc1_kernel(
    const unsigned short* __restrict__ xb, const unsigned short* __restrict__ W1t,
    const float* __restrict__ b1, const int* __restrict__ counts,
    const int* __restrict__ offsets, const int* __restrict__ slot_tok,
    const int* __restrict__ rb_ge, const int* __restrict__ rb_by,
    const int* __restrict__ nrb, unsigned short* __restrict__ H)
{
  __shared__ __align__(16) unsigned char lds[2 * 16384];
  gemm_body<DDIM, MDIM, 0, 1, 1>(lds, xb, W1t, b1, counts, offsets, nullptr,
                                 slot_tok, rb_ge, rb_by, nrb, H, nullptr,
                                 blockIdx.x, blockIdx.y, 0);
}

__global__ __launch_bounds__(256, 4) void fc2_kernel(
    const unsigned short* __restrict__ H, const unsigned short* __restrict__ W2t,
    const float* __restrict__ b2, const int* __restrict__ counts,
    const int* __restrict__ offsets, const float* __restrict__ slot_w,
    const int* __restrict__ slot_tok, const int* __restrict__ rb_ge,
    const int* __restrict__ rb_by, const int* __restrict__ nrb,
    float* __restrict__ y)
{
  __shared__ __align__(16) unsigned char lds[2 * 16384];
  gemm_body<MDIM, DDIM, 1, 0, 2>(lds, H, W2t, b2, counts, offsets, slot_w,
                                 slot_tok, rb_ge, rb_by, nrb, nullptr, y,
                                 blockIdx.x, blockIdx.y, blockIdx.z);
}

// ---------------------------------------------------------------------------
// Workspace layout (bytes):
//   0    counts[32]     128  offsets[32]    256  cursor[32]   384 nrb
//   512  rb_ge[96]      896  rb_by[96]
//   2048 pair_e[8192]   34816 pair_w[8192]
//   67584 slot_tok[8192] 100352 slot_w[8192]
//   135168 xb[1024][768] bf16 (1.57 MB)
//   12715008 H[8192][3072] bf16 (50.3 MB)
//   63046656  W1t bf16 151 MB
//   214041600 W2t bf16 151 MB      total ~365 MB (ws ~1.2 GB)
// ---------------------------------------------------------------------------
extern "C" void kernel_launch(void* const* d_in, const int* in_sizes, int n_in,
                              void* d_out, int out_size, void* d_ws, size_t ws_size,
                              hipStream_t stream)
{
  const float* x  = (const float*)d_in[0];
  const float* Wg = (const float*)d_in[1];
  const float* bg = (const float*)d_in[2];
  const float* We = (const float*)d_in[3];
  const float* be = (const float*)d_in[4];
  const float* W1 = (const float*)d_in[5];
  const float* b1 = (const float*)d_in[6];
  const float* W2 = (const float*)d_in[7];
  const float* b2 = (const float*)d_in[8];
  float* y = (float*)d_out;

  char* ws = (char*)d_ws;
  int*   counts   = (int*)(ws + 0);
  int*   offsets  = (int*)(ws + 128);
  int*   cursor   = (int*)(ws + 256);
  int*   nrb      = (int*)(ws + 384);
  int*   rb_ge    = (int*)(ws + 512);
  int*   rb_by    = (int*)(ws + 896);
  int*   pair_e   = (int*)(ws + 2048);
  float* pair_w   = (float*)(ws + 34816);
  int*   slot_tok = (int*)(ws + 67584);
  float* slot_w   = (float*)(ws + 100352);
  unsigned short* xb  = (unsigned short*)(ws + 135168);
  unsigned short* H   = (unsigned short*)(ws + 12715008);
  unsigned short* W1t = (unsigned short*)(ws + 63046656);
  unsigned short* W2t = (unsigned short*)(ws + 214041600);

  // Phase 1: prep + gating + BOTH weight repacks in one launch (overlapped).
  phase1_kernel<<<961 + 1024 + 2 * 73728, 256, 0, stream>>>(
      x, xb, y, (int*)ws, Wg, bg, We, be, counts, pair_e, pair_w,
      W1, W1t, W2, W2t);
  scan_kernel<<<1, 64, 0, stream>>>(counts, offsets, rb_ge, rb_by, nrb);
  scatter_kernel<<<NPAIR / 256, 256, 0, stream>>>(pair_e, pair_w, offsets, cursor,
                                                  slot_tok, slot_w);
  // FC1: 96 rb x 24 nb.
  fc1_kernel<<<dim3(MAXRB, MDIM / 128), 256, 0, stream>>>(
      xb, W1t, b1, counts, offsets, slot_tok, rb_ge, rb_by, nrb, H);
  // FC2: 96 rb x 6 nb x K-split 2.
  fc2_kernel<<<dim3(MAXRB, DDIM / 128, 2), 256, 0, stream>>>(
      H, W2t, b2, counts, offsets, slot_w, slot_tok, rb_ge, rb_by, nrb, y);
}